// Round 10
// baseline (356.632 us; speedup 1.0000x reference)
//
#include <hip/hip_runtime.h>
#include <stdint.h>
#include <math.h>

#define NS 32   // nsample
// S = 4, oc = 32 for layers 1..7 (5*oc = 160 fout cols), layer 8: oc=1024 (5120 cols)

// ---------------- threefry2x32 (exact JAX semantics) ----------------
__device__ __forceinline__ void threefry(uint32_t k0, uint32_t k1,
                                         uint32_t x0, uint32_t x1,
                                         uint32_t& o0, uint32_t& o1)
{
    uint32_t ks0 = k0, ks1 = k1, ks2 = k0 ^ k1 ^ 0x1BD11BDAu;
    x0 += ks0; x1 += ks1;
    const int rotA[4] = {13, 15, 26, 6};
    const int rotB[4] = {17, 29, 16, 24};
    uint32_t ks[3] = {ks0, ks1, ks2};
#pragma unroll
    for (int i = 0; i < 5; ++i) {
        const int* r = (i & 1) ? rotB : rotA;
#pragma unroll
        for (int j = 0; j < 4; ++j) {
            x0 += x1;
            x1 = (x1 << r[j]) | (x1 >> (32 - r[j]));
            x1 ^= x0;
        }
        x0 += ks[(i + 1) % 3];
        x1 += ks[(i + 2) % 3] + (uint32_t)(i + 1);
    }
    o0 = x0; o1 = x1;
}

__device__ __forceinline__ uint32_t perm_key(uint32_t seed, int round, uint32_t i)
{
    uint32_t k0 = 0u, k1 = seed;
    for (int r = 0; r < round; ++r) {           // key chain: key = TF(key,(0,0))
        uint32_t a0, a1;
        threefry(k0, k1, 0u, 0u, a0, a1);
        k0 = a0; k1 = a1;
    }
    uint32_t s0, s1;
    threefry(k0, k1, 0u, 1u, s0, s1);           // subkey = TF(key,(0,1))
    uint32_t y0, y1;
    threefry(s0, s1, 0u, i, y0, y1);            // counter hi=0, lo=i
    return y0 ^ y1;
}

// all three key arrays in one launch
__global__ void perm_genkeys_all(uint32_t* __restrict__ keys1, uint32_t* __restrict__ keys1b,
                                 uint32_t* __restrict__ keys2,
                                 int* __restrict__ valA, int* __restrict__ v2A)
{
    int blk = blockIdx.x, t = threadIdx.x;
    if (blk < 16) {
        int i = blk * 256 + t;
        keys1[i] = perm_key(1u, 0, (uint32_t)i);
        valA[i] = i;
    } else if (blk < 32) {
        int i = (blk - 16) * 256 + t;
        keys1b[i] = perm_key(1u, 1, (uint32_t)i);
    } else {
        int i = (blk - 32) * 256 + t;
        keys2[i] = perm_key(2u, 0, (uint32_t)i);
        v2A[i] = i;
    }
}

// stable ascending rank-scatter, wave-parallel: one wave per element.
template <int N>
__global__ void perm_rank(const uint32_t* __restrict__ keys,
                          const int* __restrict__ vin, int* __restrict__ vout)
{
    __shared__ uint32_t sk[N];
    for (int j = threadIdx.x; j < N; j += blockDim.x) sk[j] = keys[j];
    __syncthreads();
    int w = threadIdx.x >> 6, lane = threadIdx.x & 63;
    int i = blockIdx.x * 4 + w;
    uint32_t k = sk[i];
    int c = 0;
    for (int j = lane; j < N; j += 64) {
        uint32_t kj = sk[j];
        c += (int)((kj < k) | ((kj == k) & (j < i)));
    }
#pragma unroll
    for (int m = 1; m < 64; m <<= 1) c += __shfl_xor(c, m, 64);
    if (lane == 0) vout[c] = vin[i];
}

// rank for N=4096 (blocks 0..1023) and N=1024 (blocks 1024..1279) in one launch
__global__ void perm_rank_dual(const uint32_t* __restrict__ kA, const int* __restrict__ vinA,
                               int* __restrict__ voutA,
                               const uint32_t* __restrict__ kB, const int* __restrict__ vinB,
                               int* __restrict__ voutB)
{
    __shared__ uint32_t sk[4096];
    bool jobB = (blockIdx.x >= 1024);
    const uint32_t* keys = jobB ? kB : kA;
    const int* vin = jobB ? vinB : vinA;
    int* vout = jobB ? voutB : voutA;
    int N = jobB ? 1024 : 4096;
    int base = jobB ? (blockIdx.x - 1024) : blockIdx.x;
    for (int j = threadIdx.x; j < N; j += blockDim.x) sk[j] = keys[j];
    __syncthreads();
    int w = threadIdx.x >> 6, lane = threadIdx.x & 63;
    int i = base * 4 + w;
    uint32_t k = sk[i];
    int c = 0;
    for (int j = lane; j < N; j += 64) {
        uint32_t kj = sk[j];
        c += (int)((kj < k) | ((kj == k) & (j < i)));
    }
#pragma unroll
    for (int m = 1; m < 64; m <<= 1) c += __shfl_xor(c, m, 64);
    if (lane == 0) vout[c] = vin[i];
}

// ---------------- wave-parallel query_ball_point + neighbor directions ----------------
__global__ void qbp_wave_kernel(const float* __restrict__ pts, int Vv, float r2,
                                int* __restrict__ idx, float* __restrict__ nd)
{
#pragma clang fp contract(off)
    int b = blockIdx.y;
    int v = blockIdx.x * 4 + (threadIdx.x >> 6);
    int lane = threadIdx.x & 63;
    if (v >= Vv) return;
    const float* P = pts + (size_t)b * Vv * 3;
    float qx = P[v * 3 + 0], qy = P[v * 3 + 1], qz = P[v * 3 + 2];
    float aa = (qx * qx + qy * qy) + qz * qz;
    int* orow = idx + ((size_t)b * Vv + v) * NS;
    float* nrow = nd + ((size_t)b * Vv + v) * NS * 3;
    int cnt = 0;
    int fj = 0; float fx = 0.f, fy = 0.f, fz = 0.f;
    bool have_first = false;
    for (int j0 = 0; j0 < Vv; j0 += 64) {       // Vv is a multiple of 64
        int j = j0 + lane;
        float px = P[j * 3 + 0], py = P[j * 3 + 1], pz = P[j * 3 + 2];
        float bb2 = (px * px + py * py) + pz * pz;
        float dot = (qx * px + qy * py) + qz * pz;
        float d2 = (aa + bb2) - 2.0f * dot;     // matches aa+bb-2*einsum
        bool in = (d2 <= r2);                   // reference masks d2 > r^2
        unsigned long long m = __ballot(in);
        if (m) {
            float dx = px - qx, dy = py - qy, dz = pz - qz;
            float nn = sqrtf((dx * dx + dy * dy) + dz * dz);
            float mm = fmaxf(nn, 1e-12f);
            float ndx = dx / mm, ndy = dy / mm, ndz = dz / mm;
            int rank = __popcll(m & ((1ULL << lane) - 1ULL));
            int pos = cnt + rank;
            if (in && pos < NS) {
                orow[pos] = j;
                nrow[pos * 3 + 0] = ndx;
                nrow[pos * 3 + 1] = ndy;
                nrow[pos * 3 + 2] = ndz;
            }
            if (!have_first) {
                int src = __ffsll((unsigned long long)m) - 1;
                fj = __shfl(j, src, 64);
                fx = __shfl(ndx, src, 64);
                fy = __shfl(ndy, src, 64);
                fz = __shfl(ndz, src, 64);
                have_first = true;
            }
            cnt += (int)__popcll(m);
            if (cnt >= NS) break;
        }
    }
    if (cnt < NS) {                             // pad with first neighbor
        int k = cnt + lane;
        if (k < NS) {
            orow[k] = fj;
            nrow[k * 3 + 0] = fx; nrow[k * 3 + 1] = fy; nrow[k * 3 + 2] = fz;
        }
    }
}

// ---------------- conv_surface, wave-per-vertex (oc=32, 128 dir cols) ----------------
__global__ void conv_surface_wave(const float* __restrict__ nd, const float* __restrict__ dirs,
                                  float* __restrict__ fm, int Vv, int Cstr, int coff)
{
    __shared__ float snd[4][96];
    int b = blockIdx.y, t = threadIdx.x;
    int wid = t >> 6, lane = t & 63;
    int v = blockIdx.x * 4 + wid;
    size_t row = (size_t)b * Vv + v;
    const float* src = nd + row * NS * 3;
    snd[wid][lane] = src[lane];
    if (lane < 32) snd[wid][64 + lane] = src[64 + lane];
    __syncthreads();
    int c = lane & 31, sh = lane >> 5;
    int t1 = sh * 32 + c, t2 = t1 + 64;
    float w0a = dirs[t1], w1a = dirs[128 + t1], w2a = dirs[256 + t1];
    float w0b = dirs[t2], w1b = dirs[128 + t2], w2b = dirs[256 + t2];
    float na = fmaxf(sqrtf(w0a * w0a + w1a * w1a + w2a * w2a), 1e-12f);
    float nb = fmaxf(sqrtf(w0b * w0b + w1b * w1b + w2b * w2b), 1e-12f);
    w0a /= na; w1a /= na; w2a /= na;
    w0b /= nb; w1b /= nb; w2b /= nb;
    float mx1 = -INFINITY, mx2 = -INFINITY;
#pragma unroll
    for (int n = 0; n < NS; ++n) {
        float a0 = snd[wid][n * 3], a1 = snd[wid][n * 3 + 1], a2 = snd[wid][n * 3 + 2];
        mx1 = fmaxf(mx1, fmaxf(a0 * w0a + a1 * w1a + a2 * w2a, 0.0f));
        mx2 = fmaxf(mx2, fmaxf(a0 * w0b + a1 * w1b + a2 * w2b, 0.0f));
    }
    float sum = mx1 + mx2;
    sum += __shfl_xor(sum, 32, 64);
    if (sh == 0)
        fm[row * Cstr + coff + c] = fmaxf(sum, 0.0f);   // outer relu
}

// ---------------- tiled GEMM: C[rows x N] = A[rows x K (stride lda)] @ W[K x N] + b ----
__global__ void gemm_kernel(const float* __restrict__ A, const float* __restrict__ W,
                            const float* __restrict__ bias, float* __restrict__ C,
                            int K, int N, int lda)
{
    const int BM = 128, BN = 32, BK = 32;
    __shared__ float sA[BK][BM + 4];
    __shared__ float sB[BK][BN + 4];
    int t = threadIdx.x;
    int bm = blockIdx.y * BM, bn = blockIdx.x * BN;
    int tm = t & 31, tn = t >> 5;
    float acc[4][4] = {{0.f}};
    for (int k0 = 0; k0 < K; k0 += BK) {
#pragma unroll
        for (int i = 0; i < 4; ++i) {
            int q = t + i * 256;
            int m = q >> 3, kq = q & 7;
            float4 a = *(const float4*)&A[(size_t)(bm + m) * lda + k0 + kq * 4];
            sA[kq * 4 + 0][m] = a.x;
            sA[kq * 4 + 1][m] = a.y;
            sA[kq * 4 + 2][m] = a.z;
            sA[kq * 4 + 3][m] = a.w;
        }
        {
            int n4 = t & 7, k = t >> 3;
            float4 bv = *(const float4*)&W[(size_t)(k0 + k) * N + bn + n4 * 4];
            *(float4*)&sB[k][n4 * 4] = bv;
        }
        __syncthreads();
#pragma unroll
        for (int k = 0; k < BK; ++k) {
            float4 a4 = *(const float4*)&sA[k][tm * 4];
            float4 b4 = *(const float4*)&sB[k][tn * 4];
            float av[4] = {a4.x, a4.y, a4.z, a4.w};
            float bv[4] = {b4.x, b4.y, b4.z, b4.w};
#pragma unroll
            for (int i = 0; i < 4; ++i)
#pragma unroll
                for (int j = 0; j < 4; ++j)
                    acc[i][j] += av[i] * bv[j];
        }
        __syncthreads();
    }
    float4 bb = *(const float4*)&bias[bn + tn * 4];
    float bvv[4] = {bb.x, bb.y, bb.z, bb.w};
#pragma unroll
    for (int i = 0; i < 4; ++i) {
        float4 o;
        o.x = acc[i][0] + bvv[0];
        o.y = acc[i][1] + bvv[1];
        o.z = acc[i][2] + bvv[2];
        o.w = acc[i][3] + bvv[3];
        *(float4*)&C[(size_t)(bm + tm * 4 + i) * N + bn + tn * 4] = o;
    }
}

// ---------------- conv_layer act, wave-per-vertex (oc=32) ----------------
__global__ void act32_wave(const float* __restrict__ nd, const int* __restrict__ idx,
                           const float* __restrict__ fout, const float* __restrict__ dirs,
                           float* __restrict__ fm, int Vv, int Cstr, int coff, int dorelu)
{
    __shared__ float snd[4][96];
    __shared__ int sidx[4][32];
    int b = blockIdx.y, t = threadIdx.x;
    int wid = t >> 6, lane = t & 63;
    int v = blockIdx.x * 4 + wid;
    size_t row = (size_t)b * Vv + v;
    const float* src = nd + row * NS * 3;
    const int* irow = idx + row * NS;
    snd[wid][lane] = src[lane];
    if (lane < 32) snd[wid][64 + lane] = src[64 + lane];
    else sidx[wid][lane - 32] = irow[lane - 32];
    __syncthreads();
    int c = lane & 31, sh = lane >> 5;
    int t1 = sh * 32 + c, t2 = t1 + 64;
    float w0a = dirs[t1], w1a = dirs[128 + t1], w2a = dirs[256 + t1];
    float w0b = dirs[t2], w1b = dirs[128 + t2], w2b = dirs[256 + t2];
    float na = fmaxf(sqrtf(w0a * w0a + w1a * w1a + w2a * w2a), 1e-12f);
    float nb = fmaxf(sqrtf(w0b * w0b + w1b * w1b + w2b * w2b), 1e-12f);
    w0a /= na; w1a /= na; w2a /= na;
    w0b /= nb; w1b /= nb; w2b /= nb;
    const float* fb = fout + (size_t)b * Vv * 160;
    float mx1 = -INFINITY, mx2 = -INFINITY;
    for (int n = 0; n < NS; ++n) {
        float a0 = snd[wid][n * 3], a1 = snd[wid][n * 3 + 1], a2 = snd[wid][n * 3 + 2];
        const float* sup = fb + (size_t)sidx[wid][n] * 160 + 32;
        float th1 = fmaxf(a0 * w0a + a1 * w1a + a2 * w2a, 0.0f);
        float th2 = fmaxf(a0 * w0b + a1 * w1b + a2 * w2b, 0.0f);
        mx1 = fmaxf(mx1, th1 * sup[t1]);
        mx2 = fmaxf(mx2, th2 * sup[t2]);
    }
    float sum = mx1 + mx2;
    sum += __shfl_xor(sum, 32, 64);
    if (sh == 0) {
        float o = fout[row * 160 + c] + sum;           // center + act
        if (dorelu) o = fmaxf(o, 0.0f);
        fm[row * Cstr + coff + c] = o;
    }
}

// ---------------- pool: gather-max over first 4 neighbors at permuted rows ----------------
__global__ void pool_kernel(const float* __restrict__ fmin, const int* __restrict__ idxp,
                            const int* __restrict__ perm, const float* __restrict__ vin,
                            float* __restrict__ fmout, float* __restrict__ vout,
                            int Vin, int Vout, int Cin, int Cout)
{
    int b = blockIdx.y, nv = blockIdx.x, t = threadIdx.x;
    int pv = perm[nv];
    size_t inrow = (size_t)b * Vin + pv;
    const int* ir = idxp + inrow * NS;
    int j0 = ir[0], j1 = ir[1], j2 = ir[2], j3 = ir[3];
    if (t < Cin) {
        const float* base = fmin + (size_t)b * Vin * Cin;
        float m = base[(size_t)j0 * Cin + t];
        m = fmaxf(m, base[(size_t)j1 * Cin + t]);
        m = fmaxf(m, base[(size_t)j2 * Cin + t]);
        m = fmaxf(m, base[(size_t)j3 * Cin + t]);
        fmout[((size_t)b * Vout + nv) * Cout + t] = m;
    }
    if (t == 0) {
        vout[((size_t)b * Vout + nv) * 3 + 0] = vin[inrow * 3 + 0];
        vout[((size_t)b * Vout + nv) * 3 + 1] = vin[inrow * 3 + 1];
        vout[((size_t)b * Vout + nv) * 3 + 2] = vin[inrow * 3 + 2];
    }
}

// ---------------- layer-8 act fused with per-chunk global max (fm8 never stored) ----
// 1024 blocks: wq=u&3 (col group of 256), b=(u>>2)&1, vc=u>>3 in [0,128) — 2 vertices each.
// writes gpart[b][vc][wq*256+t] = max over the 2 vertices.
__global__ void act8_gmax_kernel(const float* __restrict__ nd3, const int* __restrict__ idx3,
                                 const float* __restrict__ fout8, const float* __restrict__ dir8,
                                 float* __restrict__ gpart)
{
    __shared__ float sd0[1024], sd1[1024], sd2[1024];   // 12 KB
    __shared__ float snd[96];
    __shared__ int sidx[32];
    int u = blockIdx.x, t = threadIdx.x;
    int wq = u & 3, b = (u >> 2) & 1, vc = u >> 3;
#pragma unroll
    for (int j = 0; j < 4; ++j) {
        int k = t + 256 * wq + 1024 * j;
        float w0 = dir8[k], w1 = dir8[4096 + k], w2 = dir8[8192 + k];
        float mm = fmaxf(sqrtf(w0 * w0 + w1 * w1 + w2 * w2), 1e-12f);
        sd0[j * 256 + t] = w0 / mm;
        sd1[j * 256 + t] = w1 / mm;
        sd2[j * 256 + t] = w2 / mm;
    }
    float vmax = -INFINITY;
    for (int vv = 0; vv < 2; ++vv) {
        int v = vc * 2 + vv;
        size_t row = (size_t)b * 256 + v;
        __syncthreads();
        if (t < 96) snd[t] = nd3[row * 96 + t];
        else if (t < 128) sidx[t - 96] = idx3[row * NS + (t - 96)];
        __syncthreads();
        float m0 = -INFINITY, m1 = -INFINITY, m2 = -INFINITY, m3 = -INFINITY;
        for (int n = 0; n < NS; ++n) {
            float a0 = snd[n * 3], a1 = snd[n * 3 + 1], a2 = snd[n * 3 + 2];
            const float* sup = fout8 + ((size_t)b * 256 + sidx[n]) * 5120 + 1024 + 256 * wq;
            float th0 = fmaxf(a0 * sd0[t] + a1 * sd1[t] + a2 * sd2[t], 0.0f);
            float th1 = fmaxf(a0 * sd0[256 + t] + a1 * sd1[256 + t] + a2 * sd2[256 + t], 0.0f);
            float th2 = fmaxf(a0 * sd0[512 + t] + a1 * sd1[512 + t] + a2 * sd2[512 + t], 0.0f);
            float th3 = fmaxf(a0 * sd0[768 + t] + a1 * sd1[768 + t] + a2 * sd2[768 + t], 0.0f);
            m0 = fmaxf(m0, th0 * sup[t]);
            m1 = fmaxf(m1, th1 * sup[t + 1024]);
            m2 = fmaxf(m2, th2 * sup[t + 2048]);
            m3 = fmaxf(m3, th3 * sup[t + 3072]);
        }
        float act = ((m0 + m1) + m2) + m3;
        int c = wq * 256 + t;
        vmax = fmaxf(vmax, fout8[row * 5120 + c] + act);
    }
    gpart[((size_t)b * 128 + vc) * 1024 + wq * 256 + t] = vmax;
}

// ---------------- head stage 1 (fuses final 128-way gmax): h = relu(BN(gfeat@cw1+cb1)) ----
__global__ void head1_kernel(const float* __restrict__ gpart,
                             const float* __restrict__ cw1, const float* __restrict__ cb1,
                             const float* __restrict__ bg, const float* __restrict__ bbv,
                             float* __restrict__ h)
{
    __shared__ float sg[1024];
    __shared__ float sp[16][17];
    int b = blockIdx.y, c0 = blockIdx.x * 16, t = threadIdx.x;
    for (int i = t; i < 1024; i += 256) {
        float m = -INFINITY;
        for (int vc = 0; vc < 128; ++vc)
            m = fmaxf(m, gpart[((size_t)b * 128 + vc) * 1024 + i]);
        sg[i] = m;
    }
    __syncthreads();
    int kg = t >> 4, cl = t & 15;
    float acc = 0.f;
#pragma unroll 8
    for (int i = 0; i < 64; ++i) {
        int k = kg * 64 + i;
        acc += sg[k] * cw1[k * 256 + c0 + cl];
    }
    sp[kg][cl] = acc;
    __syncthreads();
    if (t < 16) {
        float a = 0.f;
#pragma unroll
        for (int g = 0; g < 16; ++g) a += sp[g][t];
        int c = c0 + t;
        float hv = a + cb1[c];
        const float s = sqrtf((float)(1.0 + 1e-5));
        hv = hv / s * bg[c] + bbv[c];
        h[b * 256 + c] = fmaxf(hv, 0.0f);
    }
}

// ---------------- head stage 2: out = h @ cw2 + cb2 ----------------
__global__ void head2_kernel(const float* __restrict__ h,
                             const float* __restrict__ cw2, const float* __restrict__ cb2,
                             float* __restrict__ out)
{
    __shared__ float sh[256];
    int b = blockIdx.x, t = threadIdx.x;
    sh[t] = h[b * 256 + t];
    __syncthreads();
    if (t < 40) {
        float a = 0.f;
        for (int i = 0; i < 256; ++i) a += sh[i] * cw2[i * 40 + t];
        out[b * 40 + t] = a + cb2[t];
    }
}

// ==================================================================
extern "C" void kernel_launch(void* const* d_in, const int* in_sizes, int n_in,
                              void* d_out, int out_size, void* d_ws, size_t ws_size,
                              hipStream_t stream)
{
    (void)in_sizes; (void)n_in; (void)out_size; (void)ws_size;
    const float* vertices = (const float*)d_in[0];
    const float* d0 = (const float*)d_in[1];
    const float *w[9], *bw[9], *dir[9];
    for (int i = 1; i <= 8; ++i) {
        w[i]   = (const float*)d_in[2 + (i - 1) * 3];
        bw[i]  = (const float*)d_in[3 + (i - 1) * 3];
        dir[i] = (const float*)d_in[4 + (i - 1) * 3];
    }
    const float* cw1 = (const float*)d_in[26];
    const float* cb1 = (const float*)d_in[27];
    const float* bg  = (const float*)d_in[28];
    const float* bbv = (const float*)d_in[29];
    const float* cw2 = (const float*)d_in[30];
    const float* cb2 = (const float*)d_in[31];
    float* out = (float*)d_out;

    char* ws = (char*)d_ws;
    size_t off = 0;
    auto take = [&](size_t bytes) -> char* {
        char* p = ws + off;
        off = (off + bytes + 255) & ~(size_t)255;
        return p;
    };
    uint32_t* keys1  = (uint32_t*)take(4096 * 4);
    uint32_t* keys1b = (uint32_t*)take(4096 * 4);
    int* valA = (int*)take(4096 * 4);
    int* valB = (int*)take(4096 * 4);
    uint32_t* keys2 = (uint32_t*)take(1024 * 4);
    int* v2A = (int*)take(1024 * 4);
    int* v2B = (int*)take(1024 * 4);
    int*   idx1 = (int*)take((size_t)2 * 4096 * NS * 4);
    float* nd1  = (float*)take((size_t)2 * 4096 * NS * 3 * 4);
    float* fmA  = (float*)take((size_t)2 * 4096 * 96 * 4);
    float* vtxB = (float*)take((size_t)2 * 1024 * 3 * 4);
    int*   idx2 = (int*)take((size_t)2 * 1024 * NS * 4);
    float* nd2  = (float*)take((size_t)2 * 1024 * NS * 3 * 4);
    float* fmB  = (float*)take((size_t)2 * 1024 * 192 * 4);
    float* vtxC = (float*)take((size_t)2 * 256 * 3 * 4);
    int*   idx3 = (int*)take((size_t)2 * 256 * NS * 4);
    float* nd3  = (float*)take((size_t)2 * 256 * NS * 3 * 4);
    float* fmC  = (float*)take((size_t)2 * 256 * 256 * 4);
    float* gpart = (float*)take((size_t)2 * 128 * 1024 * 4);
    float* hbuf  = (float*)take(2 * 256 * 4);
    float* fout = (float*)take((size_t)512 * 5120 * 4);  // shared by all fout layers

    // permutations (partitionable threefry; 2 sort rounds for n=4096, 1 for n=1024)
    perm_genkeys_all<<<36, 256, 0, stream>>>(keys1, keys1b, keys2, valA, v2A);
    perm_rank_dual<<<1280, 256, 0, stream>>>(keys1, valA, valB, keys2, v2A, v2B);
    perm_rank<4096><<<1024, 256, 0, stream>>>(keys1b, valB, valA);  // perm1 = valA[:1024]; perm2 = v2B[:256]

    const float r2a = (float)(0.2 * 0.2), r2b = (float)(0.4 * 0.4), r2c = (float)(0.6 * 0.6);

    // ---- stage 1: V=4096 ----
    qbp_wave_kernel<<<dim3(1024, 2), 256, 0, stream>>>(vertices, 4096, r2a, idx1, nd1);
    conv_surface_wave<<<dim3(1024, 2), 256, 0, stream>>>(nd1, d0, fmA, 4096, 96, 0);
    gemm_kernel<<<dim3(5, 64), 256, 0, stream>>>(fmA, w[1], bw[1], fout, 32, 160, 96);
    act32_wave<<<dim3(1024, 2), 256, 0, stream>>>(nd1, idx1, fout, dir[1], fmA, 4096, 96, 32, 1);
    gemm_kernel<<<dim3(5, 64), 256, 0, stream>>>(fmA, w[2], bw[2], fout, 64, 160, 96);
    act32_wave<<<dim3(1024, 2), 256, 0, stream>>>(nd1, idx1, fout, dir[2], fmA, 4096, 96, 64, 1);
    pool_kernel<<<dim3(1024, 2), 128, 0, stream>>>(fmA, idx1, valA, vertices, fmB, vtxB, 4096, 1024, 96, 192);

    // ---- stage 2: V=1024 ----
    qbp_wave_kernel<<<dim3(256, 2), 256, 0, stream>>>(vtxB, 1024, r2b, idx2, nd2);
    gemm_kernel<<<dim3(5, 16), 256, 0, stream>>>(fmB, w[3], bw[3], fout, 96, 160, 192);
    act32_wave<<<dim3(256, 2), 256, 0, stream>>>(nd2, idx2, fout, dir[3], fmB, 1024, 192, 96, 1);
    gemm_kernel<<<dim3(5, 16), 256, 0, stream>>>(fmB, w[4], bw[4], fout, 128, 160, 192);
    act32_wave<<<dim3(256, 2), 256, 0, stream>>>(nd2, idx2, fout, dir[4], fmB, 1024, 192, 128, 1);
    gemm_kernel<<<dim3(5, 16), 256, 0, stream>>>(fmB, w[5], bw[5], fout, 160, 160, 192);
    act32_wave<<<dim3(256, 2), 256, 0, stream>>>(nd2, idx2, fout, dir[5], fmB, 1024, 192, 160, 1);
    pool_kernel<<<dim3(256, 2), 256, 0, stream>>>(fmB, idx2, v2B, vtxB, fmC, vtxC, 1024, 256, 192, 256);

    // ---- stage 3: V=256 ----
    qbp_wave_kernel<<<dim3(64, 2), 256, 0, stream>>>(vtxC, 256, r2c, idx3, nd3);
    gemm_kernel<<<dim3(5, 4), 256, 0, stream>>>(fmC, w[6], bw[6], fout, 192, 160, 256);
    act32_wave<<<dim3(64, 2), 256, 0, stream>>>(nd3, idx3, fout, dir[6], fmC, 256, 256, 192, 1);
    gemm_kernel<<<dim3(5, 4), 256, 0, stream>>>(fmC, w[7], bw[7], fout, 224, 160, 256);
    act32_wave<<<dim3(64, 2), 256, 0, stream>>>(nd3, idx3, fout, dir[7], fmC, 256, 256, 224, 1);

    // ---- layer 8 + head ----
    gemm_kernel<<<dim3(160, 4), 256, 0, stream>>>(fmC, w[8], bw[8], fout, 256, 5120, 256);
    act8_gmax_kernel<<<1024, 256, 0, stream>>>(nd3, idx3, fout, dir[8], gpart);
    head1_kernel<<<dim3(16, 2), 256, 0, stream>>>(gpart, cw1, cb1, bg, bbv, hbuf);
    head2_kernel<<<2, 256, 0, stream>>>(hbuf, cw2, cb2, out);
}

// Round 11
// 277.177 us; speedup vs baseline: 1.2867x; 1.2867x over previous
//
#include <hip/hip_runtime.h>
#include <stdint.h>
#include <math.h>

#define NS 32   // nsample
// S = 4, oc = 32 for layers 1..7 (5*oc = 160 fout cols), layer 8: oc=1024 (5120 cols)

// ---------------- threefry2x32 (exact JAX semantics) ----------------
__device__ __forceinline__ void threefry(uint32_t k0, uint32_t k1,
                                         uint32_t x0, uint32_t x1,
                                         uint32_t& o0, uint32_t& o1)
{
    uint32_t ks0 = k0, ks1 = k1, ks2 = k0 ^ k1 ^ 0x1BD11BDAu;
    x0 += ks0; x1 += ks1;
    const int rotA[4] = {13, 15, 26, 6};
    const int rotB[4] = {17, 29, 16, 24};
    uint32_t ks[3] = {ks0, ks1, ks2};
#pragma unroll
    for (int i = 0; i < 5; ++i) {
        const int* r = (i & 1) ? rotB : rotA;
#pragma unroll
        for (int j = 0; j < 4; ++j) {
            x0 += x1;
            x1 = (x1 << r[j]) | (x1 >> (32 - r[j]));
            x1 ^= x0;
        }
        x0 += ks[(i + 1) % 3];
        x1 += ks[(i + 2) % 3] + (uint32_t)(i + 1);
    }
    o0 = x0; o1 = x1;
}

__device__ __forceinline__ uint32_t perm_key(uint32_t seed, int round, uint32_t i)
{
    uint32_t k0 = 0u, k1 = seed;
    for (int r = 0; r < round; ++r) {           // key chain: key = TF(key,(0,0))
        uint32_t a0, a1;
        threefry(k0, k1, 0u, 0u, a0, a1);
        k0 = a0; k1 = a1;
    }
    uint32_t s0, s1;
    threefry(k0, k1, 0u, 1u, s0, s1);           // subkey = TF(key,(0,1))
    uint32_t y0, y1;
    threefry(s0, s1, 0u, i, y0, y1);            // counter hi=0, lo=i
    return y0 ^ y1;
}

// order-preserving float<->int map: int atomicMax == float max (exact)
__device__ __forceinline__ int fenc(float f)
{
    int i = __float_as_int(f);
    return i < 0 ? (i ^ 0x7FFFFFFF) : i;
}
__device__ __forceinline__ float fdec(int i)
{
    return __int_as_float(i < 0 ? (i ^ 0x7FFFFFFF) : i);
}

// all three key arrays in one launch; blocks 36..43 init gfeatInt to -inf code
__global__ void perm_genkeys_all(uint32_t* __restrict__ keys1, uint32_t* __restrict__ keys1b,
                                 uint32_t* __restrict__ keys2,
                                 int* __restrict__ valA, int* __restrict__ v2A,
                                 int* __restrict__ gfeatInt)
{
    int blk = blockIdx.x, t = threadIdx.x;
    if (blk < 16) {
        int i = blk * 256 + t;
        keys1[i] = perm_key(1u, 0, (uint32_t)i);
        valA[i] = i;
    } else if (blk < 32) {
        int i = (blk - 16) * 256 + t;
        keys1b[i] = perm_key(1u, 1, (uint32_t)i);
    } else if (blk < 36) {
        int i = (blk - 32) * 256 + t;
        keys2[i] = perm_key(2u, 0, (uint32_t)i);
        v2A[i] = i;
    } else {
        gfeatInt[(blk - 36) * 256 + t] = 0x80000000;   // INT_MIN
    }
}

// stable ascending rank-scatter, wave-parallel: one wave per element.
template <int N>
__global__ void perm_rank(const uint32_t* __restrict__ keys,
                          const int* __restrict__ vin, int* __restrict__ vout)
{
    __shared__ uint32_t sk[N];
    for (int j = threadIdx.x; j < N; j += blockDim.x) sk[j] = keys[j];
    __syncthreads();
    int w = threadIdx.x >> 6, lane = threadIdx.x & 63;
    int i = blockIdx.x * 4 + w;
    uint32_t k = sk[i];
    int c = 0;
    for (int j = lane; j < N; j += 64) {
        uint32_t kj = sk[j];
        c += (int)((kj < k) | ((kj == k) & (j < i)));
    }
#pragma unroll
    for (int m = 1; m < 64; m <<= 1) c += __shfl_xor(c, m, 64);
    if (lane == 0) vout[c] = vin[i];
}

// rank for N=4096 (blocks 0..1023) and N=1024 (blocks 1024..1279) in one launch
__global__ void perm_rank_dual(const uint32_t* __restrict__ kA, const int* __restrict__ vinA,
                               int* __restrict__ voutA,
                               const uint32_t* __restrict__ kB, const int* __restrict__ vinB,
                               int* __restrict__ voutB)
{
    __shared__ uint32_t sk[4096];
    bool jobB = (blockIdx.x >= 1024);
    const uint32_t* keys = jobB ? kB : kA;
    const int* vin = jobB ? vinB : vinA;
    int* vout = jobB ? voutB : voutA;
    int N = jobB ? 1024 : 4096;
    int base = jobB ? (blockIdx.x - 1024) : blockIdx.x;
    for (int j = threadIdx.x; j < N; j += blockDim.x) sk[j] = keys[j];
    __syncthreads();
    int w = threadIdx.x >> 6, lane = threadIdx.x & 63;
    int i = base * 4 + w;
    uint32_t k = sk[i];
    int c = 0;
    for (int j = lane; j < N; j += 64) {
        uint32_t kj = sk[j];
        c += (int)((kj < k) | ((kj == k) & (j < i)));
    }
#pragma unroll
    for (int m = 1; m < 64; m <<= 1) c += __shfl_xor(c, m, 64);
    if (lane == 0) vout[c] = vin[i];
}

// ---------------- wave-parallel query_ball_point + neighbor directions ----------------
__global__ void qbp_wave_kernel(const float* __restrict__ pts, int Vv, float r2,
                                int* __restrict__ idx, float* __restrict__ nd)
{
#pragma clang fp contract(off)
    int b = blockIdx.y;
    int v = blockIdx.x * 4 + (threadIdx.x >> 6);
    int lane = threadIdx.x & 63;
    if (v >= Vv) return;
    const float* P = pts + (size_t)b * Vv * 3;
    float qx = P[v * 3 + 0], qy = P[v * 3 + 1], qz = P[v * 3 + 2];
    float aa = (qx * qx + qy * qy) + qz * qz;
    int* orow = idx + ((size_t)b * Vv + v) * NS;
    float* nrow = nd + ((size_t)b * Vv + v) * NS * 3;
    int cnt = 0;
    int fj = 0; float fx = 0.f, fy = 0.f, fz = 0.f;
    bool have_first = false;
    for (int j0 = 0; j0 < Vv; j0 += 64) {       // Vv is a multiple of 64
        int j = j0 + lane;
        float px = P[j * 3 + 0], py = P[j * 3 + 1], pz = P[j * 3 + 2];
        float bb2 = (px * px + py * py) + pz * pz;
        float dot = (qx * px + qy * py) + qz * pz;
        float d2 = (aa + bb2) - 2.0f * dot;     // matches aa+bb-2*einsum
        bool in = (d2 <= r2);                   // reference masks d2 > r^2
        unsigned long long m = __ballot(in);
        if (m) {
            float dx = px - qx, dy = py - qy, dz = pz - qz;
            float nn = sqrtf((dx * dx + dy * dy) + dz * dz);
            float mm = fmaxf(nn, 1e-12f);
            float ndx = dx / mm, ndy = dy / mm, ndz = dz / mm;
            int rank = __popcll(m & ((1ULL << lane) - 1ULL));
            int pos = cnt + rank;
            if (in && pos < NS) {
                orow[pos] = j;
                nrow[pos * 3 + 0] = ndx;
                nrow[pos * 3 + 1] = ndy;
                nrow[pos * 3 + 2] = ndz;
            }
            if (!have_first) {
                int src = __ffsll((unsigned long long)m) - 1;
                fj = __shfl(j, src, 64);
                fx = __shfl(ndx, src, 64);
                fy = __shfl(ndy, src, 64);
                fz = __shfl(ndz, src, 64);
                have_first = true;
            }
            cnt += (int)__popcll(m);
            if (cnt >= NS) break;
        }
    }
    if (cnt < NS) {                             // pad with first neighbor
        int k = cnt + lane;
        if (k < NS) {
            orow[k] = fj;
            nrow[k * 3 + 0] = fx; nrow[k * 3 + 1] = fy; nrow[k * 3 + 2] = fz;
        }
    }
}

// ---------------- conv_surface, wave-per-vertex (oc=32, 128 dir cols) ----------------
__global__ void conv_surface_wave(const float* __restrict__ nd, const float* __restrict__ dirs,
                                  float* __restrict__ fm, int Vv, int Cstr, int coff)
{
    __shared__ float snd[4][96];
    int b = blockIdx.y, t = threadIdx.x;
    int wid = t >> 6, lane = t & 63;
    int v = blockIdx.x * 4 + wid;
    size_t row = (size_t)b * Vv + v;
    const float* src = nd + row * NS * 3;
    snd[wid][lane] = src[lane];
    if (lane < 32) snd[wid][64 + lane] = src[64 + lane];
    __syncthreads();
    int c = lane & 31, sh = lane >> 5;
    int t1 = sh * 32 + c, t2 = t1 + 64;
    float w0a = dirs[t1], w1a = dirs[128 + t1], w2a = dirs[256 + t1];
    float w0b = dirs[t2], w1b = dirs[128 + t2], w2b = dirs[256 + t2];
    float na = fmaxf(sqrtf(w0a * w0a + w1a * w1a + w2a * w2a), 1e-12f);
    float nb = fmaxf(sqrtf(w0b * w0b + w1b * w1b + w2b * w2b), 1e-12f);
    w0a /= na; w1a /= na; w2a /= na;
    w0b /= nb; w1b /= nb; w2b /= nb;
    float mx1 = -INFINITY, mx2 = -INFINITY;
#pragma unroll
    for (int n = 0; n < NS; ++n) {
        float a0 = snd[wid][n * 3], a1 = snd[wid][n * 3 + 1], a2 = snd[wid][n * 3 + 2];
        mx1 = fmaxf(mx1, fmaxf(a0 * w0a + a1 * w1a + a2 * w2a, 0.0f));
        mx2 = fmaxf(mx2, fmaxf(a0 * w0b + a1 * w1b + a2 * w2b, 0.0f));
    }
    float sum = mx1 + mx2;
    sum += __shfl_xor(sum, 32, 64);
    if (sh == 0)
        fm[row * Cstr + coff + c] = fmaxf(sum, 0.0f);   // outer relu
}

// ---------------- tiled GEMM: C[rows x N] = A[rows x K (stride lda)] @ W[K x N] + b ----
__global__ void gemm_kernel(const float* __restrict__ A, const float* __restrict__ W,
                            const float* __restrict__ bias, float* __restrict__ C,
                            int K, int N, int lda)
{
    const int BM = 128, BN = 32, BK = 32;
    __shared__ float sA[BK][BM + 4];
    __shared__ float sB[BK][BN + 4];
    int t = threadIdx.x;
    int bm = blockIdx.y * BM, bn = blockIdx.x * BN;
    int tm = t & 31, tn = t >> 5;
    float acc[4][4] = {{0.f}};
    for (int k0 = 0; k0 < K; k0 += BK) {
#pragma unroll
        for (int i = 0; i < 4; ++i) {
            int q = t + i * 256;
            int m = q >> 3, kq = q & 7;
            float4 a = *(const float4*)&A[(size_t)(bm + m) * lda + k0 + kq * 4];
            sA[kq * 4 + 0][m] = a.x;
            sA[kq * 4 + 1][m] = a.y;
            sA[kq * 4 + 2][m] = a.z;
            sA[kq * 4 + 3][m] = a.w;
        }
        {
            int n4 = t & 7, k = t >> 3;
            float4 bv = *(const float4*)&W[(size_t)(k0 + k) * N + bn + n4 * 4];
            *(float4*)&sB[k][n4 * 4] = bv;
        }
        __syncthreads();
#pragma unroll
        for (int k = 0; k < BK; ++k) {
            float4 a4 = *(const float4*)&sA[k][tm * 4];
            float4 b4 = *(const float4*)&sB[k][tn * 4];
            float av[4] = {a4.x, a4.y, a4.z, a4.w};
            float bv[4] = {b4.x, b4.y, b4.z, b4.w};
#pragma unroll
            for (int i = 0; i < 4; ++i)
#pragma unroll
                for (int j = 0; j < 4; ++j)
                    acc[i][j] += av[i] * bv[j];
        }
        __syncthreads();
    }
    float4 bb = *(const float4*)&bias[bn + tn * 4];
    float bvv[4] = {bb.x, bb.y, bb.z, bb.w};
#pragma unroll
    for (int i = 0; i < 4; ++i) {
        float4 o;
        o.x = acc[i][0] + bvv[0];
        o.y = acc[i][1] + bvv[1];
        o.z = acc[i][2] + bvv[2];
        o.w = acc[i][3] + bvv[3];
        *(float4*)&C[(size_t)(bm + tm * 4 + i) * N + bn + tn * 4] = o;
    }
}

// ---------------- conv_layer act, wave-per-vertex (oc=32) ----------------
__global__ void act32_wave(const float* __restrict__ nd, const int* __restrict__ idx,
                           const float* __restrict__ fout, const float* __restrict__ dirs,
                           float* __restrict__ fm, int Vv, int Cstr, int coff, int dorelu)
{
    __shared__ float snd[4][96];
    __shared__ int sidx[4][32];
    int b = blockIdx.y, t = threadIdx.x;
    int wid = t >> 6, lane = t & 63;
    int v = blockIdx.x * 4 + wid;
    size_t row = (size_t)b * Vv + v;
    const float* src = nd + row * NS * 3;
    const int* irow = idx + row * NS;
    snd[wid][lane] = src[lane];
    if (lane < 32) snd[wid][64 + lane] = src[64 + lane];
    else sidx[wid][lane - 32] = irow[lane - 32];
    __syncthreads();
    int c = lane & 31, sh = lane >> 5;
    int t1 = sh * 32 + c, t2 = t1 + 64;
    float w0a = dirs[t1], w1a = dirs[128 + t1], w2a = dirs[256 + t1];
    float w0b = dirs[t2], w1b = dirs[128 + t2], w2b = dirs[256 + t2];
    float na = fmaxf(sqrtf(w0a * w0a + w1a * w1a + w2a * w2a), 1e-12f);
    float nb = fmaxf(sqrtf(w0b * w0b + w1b * w1b + w2b * w2b), 1e-12f);
    w0a /= na; w1a /= na; w2a /= na;
    w0b /= nb; w1b /= nb; w2b /= nb;
    const float* fb = fout + (size_t)b * Vv * 160;
    float mx1 = -INFINITY, mx2 = -INFINITY;
    for (int n = 0; n < NS; ++n) {
        float a0 = snd[wid][n * 3], a1 = snd[wid][n * 3 + 1], a2 = snd[wid][n * 3 + 2];
        const float* sup = fb + (size_t)sidx[wid][n] * 160 + 32;
        float th1 = fmaxf(a0 * w0a + a1 * w1a + a2 * w2a, 0.0f);
        float th2 = fmaxf(a0 * w0b + a1 * w1b + a2 * w2b, 0.0f);
        mx1 = fmaxf(mx1, th1 * sup[t1]);
        mx2 = fmaxf(mx2, th2 * sup[t2]);
    }
    float sum = mx1 + mx2;
    sum += __shfl_xor(sum, 32, 64);
    if (sh == 0) {
        float o = fout[row * 160 + c] + sum;           // center + act
        if (dorelu) o = fmaxf(o, 0.0f);
        fm[row * Cstr + coff + c] = o;
    }
}

// ---------------- pool: gather-max over first 4 neighbors at permuted rows ----------------
__global__ void pool_kernel(const float* __restrict__ fmin, const int* __restrict__ idxp,
                            const int* __restrict__ perm, const float* __restrict__ vin,
                            float* __restrict__ fmout, float* __restrict__ vout,
                            int Vin, int Vout, int Cin, int Cout)
{
    int b = blockIdx.y, nv = blockIdx.x, t = threadIdx.x;
    int pv = perm[nv];
    size_t inrow = (size_t)b * Vin + pv;
    const int* ir = idxp + inrow * NS;
    int j0 = ir[0], j1 = ir[1], j2 = ir[2], j3 = ir[3];
    if (t < Cin) {
        const float* base = fmin + (size_t)b * Vin * Cin;
        float m = base[(size_t)j0 * Cin + t];
        m = fmaxf(m, base[(size_t)j1 * Cin + t]);
        m = fmaxf(m, base[(size_t)j2 * Cin + t]);
        m = fmaxf(m, base[(size_t)j3 * Cin + t]);
        fmout[((size_t)b * Vout + nv) * Cout + t] = m;
    }
    if (t == 0) {
        vout[((size_t)b * Vout + nv) * 3 + 0] = vin[inrow * 3 + 0];
        vout[((size_t)b * Vout + nv) * 3 + 1] = vin[inrow * 3 + 1];
        vout[((size_t)b * Vout + nv) * 3 + 2] = vin[inrow * 3 + 2];
    }
}

// ---------------- layer-8 act fused with global max via atomicMax (fm8 never stored) ----
// 2048 blocks, one vertex each: wq=u&3 (col group of 256), b=(u>>2)&1, v=u>>3.
// Each thread computes one output column and atomically maxes into gfeatInt[b][c].
__global__ void act8_gmax_kernel(const float* __restrict__ nd3, const int* __restrict__ idx3,
                                 const float* __restrict__ fout8, const float* __restrict__ dir8,
                                 int* __restrict__ gfeatInt)
{
    __shared__ float sd0[1024], sd1[1024], sd2[1024];   // 12 KB
    __shared__ float snd[96];
    __shared__ int sidx[32];
    int u = blockIdx.x, t = threadIdx.x;
    int wq = u & 3, b = (u >> 2) & 1, v = u >> 3;
#pragma unroll
    for (int j = 0; j < 4; ++j) {
        int k = t + 256 * wq + 1024 * j;
        float w0 = dir8[k], w1 = dir8[4096 + k], w2 = dir8[8192 + k];
        float mm = fmaxf(sqrtf(w0 * w0 + w1 * w1 + w2 * w2), 1e-12f);
        sd0[j * 256 + t] = w0 / mm;
        sd1[j * 256 + t] = w1 / mm;
        sd2[j * 256 + t] = w2 / mm;
    }
    size_t row = (size_t)b * 256 + v;
    if (t < 96) snd[t] = nd3[row * 96 + t];
    else if (t < 128) sidx[t - 96] = idx3[row * NS + (t - 96)];
    __syncthreads();
    float m0 = -INFINITY, m1 = -INFINITY, m2 = -INFINITY, m3 = -INFINITY;
    for (int n = 0; n < NS; ++n) {
        float a0 = snd[n * 3], a1 = snd[n * 3 + 1], a2 = snd[n * 3 + 2];
        const float* sup = fout8 + ((size_t)b * 256 + sidx[n]) * 5120 + 1024 + 256 * wq;
        float th0 = fmaxf(a0 * sd0[t] + a1 * sd1[t] + a2 * sd2[t], 0.0f);
        float th1 = fmaxf(a0 * sd0[256 + t] + a1 * sd1[256 + t] + a2 * sd2[256 + t], 0.0f);
        float th2 = fmaxf(a0 * sd0[512 + t] + a1 * sd1[512 + t] + a2 * sd2[512 + t], 0.0f);
        float th3 = fmaxf(a0 * sd0[768 + t] + a1 * sd1[768 + t] + a2 * sd2[768 + t], 0.0f);
        m0 = fmaxf(m0, th0 * sup[t]);
        m1 = fmaxf(m1, th1 * sup[t + 1024]);
        m2 = fmaxf(m2, th2 * sup[t + 2048]);
        m3 = fmaxf(m3, th3 * sup[t + 3072]);
    }
    float act = ((m0 + m1) + m2) + m3;
    int c = wq * 256 + t;
    float val = fout8[row * 5120 + c] + act;
    atomicMax(&gfeatInt[b * 1024 + c], fenc(val));
}

// ---------------- head stage 1: h = relu(BN(gfeat @ cw1 + cb1)) ----------------
__global__ void head1_kernel(const int* __restrict__ gfeatInt,
                             const float* __restrict__ cw1, const float* __restrict__ cb1,
                             const float* __restrict__ bg, const float* __restrict__ bbv,
                             float* __restrict__ h)
{
    __shared__ float sg[1024];
    __shared__ float sp[16][17];
    int b = blockIdx.y, c0 = blockIdx.x * 16, t = threadIdx.x;
    for (int i = t; i < 1024; i += 256)
        sg[i] = fdec(gfeatInt[b * 1024 + i]);
    __syncthreads();
    int kg = t >> 4, cl = t & 15;
    float acc = 0.f;
#pragma unroll 8
    for (int i = 0; i < 64; ++i) {
        int k = kg * 64 + i;
        acc += sg[k] * cw1[k * 256 + c0 + cl];
    }
    sp[kg][cl] = acc;
    __syncthreads();
    if (t < 16) {
        float a = 0.f;
#pragma unroll
        for (int g = 0; g < 16; ++g) a += sp[g][t];
        int c = c0 + t;
        float hv = a + cb1[c];
        const float s = sqrtf((float)(1.0 + 1e-5));
        hv = hv / s * bg[c] + bbv[c];
        h[b * 256 + c] = fmaxf(hv, 0.0f);
    }
}

// ---------------- head stage 2: out = h @ cw2 + cb2 ----------------
__global__ void head2_kernel(const float* __restrict__ h,
                             const float* __restrict__ cw2, const float* __restrict__ cb2,
                             float* __restrict__ out)
{
    __shared__ float sh[256];
    int b = blockIdx.x, t = threadIdx.x;
    sh[t] = h[b * 256 + t];
    __syncthreads();
    if (t < 40) {
        float a = 0.f;
        for (int i = 0; i < 256; ++i) a += sh[i] * cw2[i * 40 + t];
        out[b * 40 + t] = a + cb2[t];
    }
}

// ==================================================================
extern "C" void kernel_launch(void* const* d_in, const int* in_sizes, int n_in,
                              void* d_out, int out_size, void* d_ws, size_t ws_size,
                              hipStream_t stream)
{
    (void)in_sizes; (void)n_in; (void)out_size; (void)ws_size;
    const float* vertices = (const float*)d_in[0];
    const float* d0 = (const float*)d_in[1];
    const float *w[9], *bw[9], *dir[9];
    for (int i = 1; i <= 8; ++i) {
        w[i]   = (const float*)d_in[2 + (i - 1) * 3];
        bw[i]  = (const float*)d_in[3 + (i - 1) * 3];
        dir[i] = (const float*)d_in[4 + (i - 1) * 3];
    }
    const float* cw1 = (const float*)d_in[26];
    const float* cb1 = (const float*)d_in[27];
    const float* bg  = (const float*)d_in[28];
    const float* bbv = (const float*)d_in[29];
    const float* cw2 = (const float*)d_in[30];
    const float* cb2 = (const float*)d_in[31];
    float* out = (float*)d_out;

    char* ws = (char*)d_ws;
    size_t off = 0;
    auto take = [&](size_t bytes) -> char* {
        char* p = ws + off;
        off = (off + bytes + 255) & ~(size_t)255;
        return p;
    };
    uint32_t* keys1  = (uint32_t*)take(4096 * 4);
    uint32_t* keys1b = (uint32_t*)take(4096 * 4);
    int* valA = (int*)take(4096 * 4);
    int* valB = (int*)take(4096 * 4);
    uint32_t* keys2 = (uint32_t*)take(1024 * 4);
    int* v2A = (int*)take(1024 * 4);
    int* v2B = (int*)take(1024 * 4);
    int*   idx1 = (int*)take((size_t)2 * 4096 * NS * 4);
    float* nd1  = (float*)take((size_t)2 * 4096 * NS * 3 * 4);
    float* fmA  = (float*)take((size_t)2 * 4096 * 96 * 4);
    float* vtxB = (float*)take((size_t)2 * 1024 * 3 * 4);
    int*   idx2 = (int*)take((size_t)2 * 1024 * NS * 4);
    float* nd2  = (float*)take((size_t)2 * 1024 * NS * 3 * 4);
    float* fmB  = (float*)take((size_t)2 * 1024 * 192 * 4);
    float* vtxC = (float*)take((size_t)2 * 256 * 3 * 4);
    int*   idx3 = (int*)take((size_t)2 * 256 * NS * 4);
    float* nd3  = (float*)take((size_t)2 * 256 * NS * 3 * 4);
    float* fmC  = (float*)take((size_t)2 * 256 * 256 * 4);
    int*   gfeatInt = (int*)take(2 * 1024 * 4);
    float* hbuf  = (float*)take(2 * 256 * 4);
    float* fout = (float*)take((size_t)512 * 5120 * 4);  // shared by all fout layers

    // permutations (partitionable threefry; 2 sort rounds for n=4096, 1 for n=1024)
    // + gfeatInt init (blocks 36..43)
    perm_genkeys_all<<<44, 256, 0, stream>>>(keys1, keys1b, keys2, valA, v2A, gfeatInt);
    perm_rank_dual<<<1280, 256, 0, stream>>>(keys1, valA, valB, keys2, v2A, v2B);
    perm_rank<4096><<<1024, 256, 0, stream>>>(keys1b, valB, valA);  // perm1 = valA[:1024]; perm2 = v2B[:256]

    const float r2a = (float)(0.2 * 0.2), r2b = (float)(0.4 * 0.4), r2c = (float)(0.6 * 0.6);

    // ---- stage 1: V=4096 ----
    qbp_wave_kernel<<<dim3(1024, 2), 256, 0, stream>>>(vertices, 4096, r2a, idx1, nd1);
    conv_surface_wave<<<dim3(1024, 2), 256, 0, stream>>>(nd1, d0, fmA, 4096, 96, 0);
    gemm_kernel<<<dim3(5, 64), 256, 0, stream>>>(fmA, w[1], bw[1], fout, 32, 160, 96);
    act32_wave<<<dim3(1024, 2), 256, 0, stream>>>(nd1, idx1, fout, dir[1], fmA, 4096, 96, 32, 1);
    gemm_kernel<<<dim3(5, 64), 256, 0, stream>>>(fmA, w[2], bw[2], fout, 64, 160, 96);
    act32_wave<<<dim3(1024, 2), 256, 0, stream>>>(nd1, idx1, fout, dir[2], fmA, 4096, 96, 64, 1);
    pool_kernel<<<dim3(1024, 2), 128, 0, stream>>>(fmA, idx1, valA, vertices, fmB, vtxB, 4096, 1024, 96, 192);

    // ---- stage 2: V=1024 ----
    qbp_wave_kernel<<<dim3(256, 2), 256, 0, stream>>>(vtxB, 1024, r2b, idx2, nd2);
    gemm_kernel<<<dim3(5, 16), 256, 0, stream>>>(fmB, w[3], bw[3], fout, 96, 160, 192);
    act32_wave<<<dim3(256, 2), 256, 0, stream>>>(nd2, idx2, fout, dir[3], fmB, 1024, 192, 96, 1);
    gemm_kernel<<<dim3(5, 16), 256, 0, stream>>>(fmB, w[4], bw[4], fout, 128, 160, 192);
    act32_wave<<<dim3(256, 2), 256, 0, stream>>>(nd2, idx2, fout, dir[4], fmB, 1024, 192, 128, 1);
    gemm_kernel<<<dim3(5, 16), 256, 0, stream>>>(fmB, w[5], bw[5], fout, 160, 160, 192);
    act32_wave<<<dim3(256, 2), 256, 0, stream>>>(nd2, idx2, fout, dir[5], fmB, 1024, 192, 160, 1);
    pool_kernel<<<dim3(256, 2), 256, 0, stream>>>(fmB, idx2, v2B, vtxB, fmC, vtxC, 1024, 256, 192, 256);

    // ---- stage 3: V=256 ----
    qbp_wave_kernel<<<dim3(64, 2), 256, 0, stream>>>(vtxC, 256, r2c, idx3, nd3);
    gemm_kernel<<<dim3(5, 4), 256, 0, stream>>>(fmC, w[6], bw[6], fout, 192, 160, 256);
    act32_wave<<<dim3(64, 2), 256, 0, stream>>>(nd3, idx3, fout, dir[6], fmC, 256, 256, 192, 1);
    gemm_kernel<<<dim3(5, 4), 256, 0, stream>>>(fmC, w[7], bw[7], fout, 224, 160, 256);
    act32_wave<<<dim3(64, 2), 256, 0, stream>>>(nd3, idx3, fout, dir[7], fmC, 256, 256, 224, 1);

    // ---- layer 8 + head ----
    gemm_kernel<<<dim3(160, 4), 256, 0, stream>>>(fmC, w[8], bw[8], fout, 256, 5120, 256);
    act8_gmax_kernel<<<2048, 256, 0, stream>>>(nd3, idx3, fout, dir[8], gfeatInt);
    head1_kernel<<<dim3(16, 2), 256, 0, stream>>>(gfeatInt, cw1, cb1, bg, bbv, hbuf);
    head2_kernel<<<2, 256, 0, stream>>>(hbuf, cw2, cb2, out);
}